// Round 4
// baseline (372.430 us; speedup 1.0000x reference)
//
#include <hip/hip_runtime.h>
#include <hip/hip_bf16.h>
#include <math.h>

#define NH    8
#define CPH   48
#define D     384
#define QC    1152
#define HF    192
#define WFULL 192
#define HP    96
#define WP    96
#define NP    9216    // 96*96
#define NF    36864   // 192*192

typedef __attribute__((ext_vector_type(8))) short short8;
typedef __attribute__((ext_vector_type(4))) float f32x4;

__device__ __forceinline__ void fma4(float4& a, float s, const float4& v) {
    a.x += s * v.x; a.y += s * v.y; a.z += s * v.z; a.w += s * v.w;
}
__device__ __forceinline__ float gelu_exact(float v) {
    return 0.5f * v * (1.f + erff(v * 0.70710678118654752440f));
}
__device__ __forceinline__ ushort f2bf(float v) {
    __hip_bfloat16 h = __float2bfloat16(v);
    return *reinterpret_cast<ushort*>(&h);
}
__device__ __forceinline__ float bf2f(ushort u) {
    __hip_bfloat16 h = *reinterpret_cast<__hip_bfloat16*>(&u);
    return __bfloat162float(h);
}

__global__ void k_zero(float* p, int n) {
    int i = blockIdx.x * 256 + threadIdx.x;
    if (i < n) p[i] = 0.f;
}

// ---------------- P1: split w into bf16 hi/lo --------------------------------
__global__ __launch_bounds__(256) void k_prep_w(
    const float* __restrict__ w, ushort* __restrict__ wh, ushort* __restrict__ wl, int n) {
    int i = blockIdx.x * 256 + threadIdx.x;
    if (i < n) {
        float v = w[i];
        ushort h = f2bf(v);
        wh[i] = h;
        wl[i] = f2bf(v - bf2f(h));
    }
}

// ---------------- P2: split+transpose x -> [n'][c] bf16 hi/lo ---------------
// n' = (py*96+px)*4 + (y&1)*2 + (x&1)   (pool-quad-contiguous pixel order)
// Tile: 128 n' (=32 quads, within one pool row) x 64 ch.  Phase 1: float4
// coalesced loads -> linear LDS.  Phase 2: one thread = one 64B output line
// (1 n' x 32 ch): 32 LDS reads + hi/lo split + 4x16B stores per array.
__global__ __launch_bounds__(256) void k_prep_x(
    const float* __restrict__ x, ushort* __restrict__ xh, ushort* __restrict__ xl) {
    __shared__ float xf[64][128];   // [ch][r*64+col], 32 KB
    const int tid = threadIdx.x;
    const int kk = blockIdx.y * 64;
    const int q0 = blockIdx.x * 32;          // 32 pool quads (one pool row chunk)
    const int py = q0 / 96, px0 = q0 - py * 96;
    const int y0 = 2 * py, xcol0 = 2 * px0;
    const float* xb = x + (size_t)kk * NF + (size_t)y0 * WFULL + xcol0;
#pragma unroll
    for (int it = 0; it < 8; it++) {
        int li = tid + 256 * it;
        int ch = li >> 5, r = (li >> 4) & 1, c4 = (li & 15) * 4;
        float4 v = *(const float4*)&xb[(size_t)ch * NF + r * WFULL + c4];
        *(float4*)&xf[ch][r * 64 + c4] = v;
    }
    __syncthreads();
    const int row = tid >> 1, half = tid & 1;
    const int r = (row >> 1) & 1;
    const int col = (row >> 2) * 2 + (row & 1);
    const int src = r * 64 + col;
    const size_t np = (size_t)blockIdx.x * 128 + row;
    ushort hbuf[32], lbuf[32];
#pragma unroll
    for (int j = 0; j < 32; j++) {
        float v = xf[half * 32 + j][src];
        ushort h = f2bf(v);
        hbuf[j] = h;
        lbuf[j] = f2bf(v - bf2f(h));
    }
    ushort* dh = xh + np * D + kk + half * 32;
    ushort* dl = xl + np * D + kk + half * 32;
#pragma unroll
    for (int j = 0; j < 4; j++) {
        *(short8*)&dh[j * 8] = *(const short8*)&hbuf[j * 8];
        *(short8*)&dl[j * 8] = *(const short8*)&lbuf[j * 8];
    }
}

// ---------------- K1: qkv 1x1 conv as bf16x3 MFMA GEMM + fused 2x2 maxpool ---
// C[n', o] = sum_k x'[n',k] w[o,k];  M=36864(n'), N=1152(o), K=384
// 128x128 tile, BK=32, 4 waves (2x2 of 64x64), 2-bit XOR-swizzled LDS,
// global_load_lds staging, XCD-aware block remap (9 n-tiles share A panel).
__global__ __launch_bounds__(256) void k_qkv_mfma(
    const ushort* __restrict__ xh, const ushort* __restrict__ xl,
    const ushort* __restrict__ wh, const ushort* __restrict__ wl,
    const float* __restrict__ bq, float* __restrict__ pooled) {
    __shared__ ushort lds[4][4096];    // Ah, Al, Bh, Bl : 128 rows x 32 bf16 (8KB each)
    const int tid = threadIdx.x;
    const int lane = tid & 63, wid = tid >> 6;
    const int wm = wid >> 1, wn = wid & 1;

    // XCD-aware remap: dispatch d -> same-XCD chunk of 36 m-tiles x 9 n-tiles
    const int d   = blockIdx.x;        // 0..2591, HW XCD = d % 8
    const int xcd = d & 7;
    const int idx = d >> 3;            // 0..323
    const int by  = xcd * 36 + idx / 9;
    const int bx  = idx % 9;
    const int n0 = bx * 128;           // out-channel tile
    const int m0 = by * 128;           // pixel tile

    const ushort* srcs[4];
    srcs[0] = xh + (size_t)m0 * D;
    srcs[1] = xl + (size_t)m0 * D;
    srcs[2] = wh + (size_t)n0 * D;
    srcs[3] = wl + (size_t)n0 * D;

    f32x4 acc[4][4];
#pragma unroll
    for (int i = 0; i < 4; i++)
#pragma unroll
        for (int j = 0; j < 4; j++) acc[i][j] = (f32x4){0.f, 0.f, 0.f, 0.f};

    // fragment ds_read byte offsets (within one 8KB tile), 2-bit XOR swizzle:
    // chunk' = chunk ^ ((row>>1)&3); row stride 64B
    int a_off[4], b_off[4];
#pragma unroll
    for (int f = 0; f < 4; f++) {
        int ra = wm * 64 + f * 16 + (lane & 15);
        a_off[f] = ra * 64 + ((((lane >> 4) ^ ((ra >> 1) & 3)) & 3) << 4);
        int rb = wn * 64 + f * 16 + (lane & 15);
        b_off[f] = rb * 64 + ((((lane >> 4) ^ ((rb >> 1) & 3)) & 3) << 4);
    }

    for (int ks = 0; ks < 12; ks++) {
        const int kk = ks * 32;
        __syncthreads();
        // stage 32KB: 4 waves x 8 issues x 64 lanes x 16B; linear LDS dest,
        // inverse-swizzled global source (both-sides rule, 2-bit chunk XOR)
#pragma unroll
        for (int i = 0; i < 8; i++) {
            const int mat = i >> 1;
            const int cm  = ((i & 1) << 2) | wid;        // 1KB chunk within tile
            const int row = cm * 16 + (lane >> 2);
            const int scol = (((lane & 3) ^ ((row >> 1) & 3)) & 3) << 4;  // bytes, <64
            const ushort* src = srcs[mat] + (size_t)row * D + kk + (scol >> 1);
            __builtin_amdgcn_global_load_lds(
                (const __attribute__((address_space(1))) void*)src,
                (__attribute__((address_space(3))) void*)&lds[mat][cm * 512],
                16, 0, 0);
        }
        __syncthreads();   // compiler drains vmcnt before barrier

        short8 A[2][4], B[2][4];
#pragma unroll
        for (int f = 0; f < 4; f++) {
            A[0][f] = *(const short8*)((const char*)&lds[0][0] + a_off[f]);
            A[1][f] = *(const short8*)((const char*)&lds[1][0] + a_off[f]);
            B[0][f] = *(const short8*)((const char*)&lds[2][0] + b_off[f]);
            B[1][f] = *(const short8*)((const char*)&lds[3][0] + b_off[f]);
        }
#pragma unroll
        for (int fm = 0; fm < 4; fm++)
#pragma unroll
            for (int fn = 0; fn < 4; fn++) {
                acc[fm][fn] = __builtin_amdgcn_mfma_f32_16x16x32_bf16(A[0][fm], B[0][fn], acc[fm][fn], 0, 0, 0);
                acc[fm][fn] = __builtin_amdgcn_mfma_f32_16x16x32_bf16(A[0][fm], B[1][fn], acc[fm][fn], 0, 0, 0);
                acc[fm][fn] = __builtin_amdgcn_mfma_f32_16x16x32_bf16(A[1][fm], B[0][fn], acc[fm][fn], 0, 0, 0);
            }
    }

    // epilogue: 4 C-regs of each fragment = one pool quad (n' is quad-contiguous)
    const int p_base = by * 32 + wm * 16 + (lane >> 4);
#pragma unroll
    for (int fn = 0; fn < 4; fn++) {
        const int o = n0 + wn * 64 + fn * 16 + (lane & 15);
        const float b = bq[o];
#pragma unroll
        for (int fm = 0; fm < 4; fm++) {
            f32x4 v = acc[fm][fn];
            float mx = fmaxf(fmaxf(v.x, v.y), fmaxf(v.z, v.w)) + b;
            pooled[(size_t)o * NP + p_base + fm * 4] = mx;
        }
    }
}

// ---------------- K2: depthwise 3x3 conv, SAME padding -----------------------
__global__ __launch_bounds__(256) void k_dwconv(
    const float* __restrict__ pooled, const float* __restrict__ wd,
    const float* __restrict__ bd, float* __restrict__ out) {
    int gid = blockIdx.x * 256 + threadIdx.x;
    int ch = gid / NP;
    int n  = gid - ch * NP;
    int y  = n / WP;
    int x0 = n - y * WP;
    const float* src = pooled + (size_t)ch * NP;
    const float* w = wd + ch * 9;
    float s = bd[ch];
#pragma unroll
    for (int dy = 0; dy < 3; dy++) {
        int yy = y + dy - 1;
        if (yy < 0 || yy >= HP) continue;
#pragma unroll
        for (int dx = 0; dx < 3; dx++) {
            int xx = x0 + dx - 1;
            if (xx < 0 || xx >= WP) continue;
            s += src[yy * WP + xx] * w[dy * 3 + dx];
        }
    }
    out[gid] = s;
}

// ---------------- K3: attn partials S = q.k^T, plus sq-norms -----------------
__global__ __launch_bounds__(64) void k_attn(
    const float* __restrict__ qkv, float* __restrict__ S,
    float* __restrict__ qn, float* __restrict__ kn) {
    __shared__ float qs[48][97], ks[48][97];
    int t = threadIdx.x;
    int head = blockIdx.y;
    int n0 = blockIdx.x * 96;
    const float* qb = qkv + (size_t)(head * CPH) * NP + n0;
    const float* kb = qkv + (size_t)(D + head * CPH) * NP + n0;
    for (int it = 0; it < 72; it++) {
        int li = t + 64 * it;
        int col = li % 96, row = li / 96;
        qs[row][col] = qb[(size_t)row * NP + col];
        ks[row][col] = kb[(size_t)row * NP + col];
    }
    __syncthreads();
    int tr = t >> 3, tc = t & 7;
    float acc[6][6] = {};
    for (int n = 0; n < 96; n++) {
        float qv[6], kv[6];
#pragma unroll
        for (int i = 0; i < 6; i++) qv[i] = qs[tr * 6 + i][n];
#pragma unroll
        for (int j = 0; j < 6; j++) kv[j] = ks[tc * 6 + j][n];
#pragma unroll
        for (int i = 0; i < 6; i++)
#pragma unroll
            for (int j = 0; j < 6; j++) acc[i][j] += qv[i] * kv[j];
    }
    if (t < 48) {
        float sq = 0.f, sk = 0.f;
        for (int n = 0; n < 96; n++) {
            sq += qs[t][n] * qs[t][n];
            sk += ks[t][n] * ks[t][n];
        }
        atomicAdd(&qn[head * CPH + t], sq);
        atomicAdd(&kn[head * CPH + t], sk);
    }
    float* Sh = S + head * CPH * CPH;
#pragma unroll
    for (int i = 0; i < 6; i++)
#pragma unroll
        for (int j = 0; j < 6; j++)
            atomicAdd(&Sh[(tr * 6 + i) * CPH + tc * 6 + j], acc[i][j]);
}

// ---------------- K4: normalize + 4x nested top-k softmax --------------------
__global__ __launch_bounds__(256) void k_softmax(
    const float* __restrict__ S, const float* __restrict__ qn,
    const float* __restrict__ kn, const float* __restrict__ temp,
    const float* __restrict__ a1, const float* __restrict__ a2,
    const float* __restrict__ a3, const float* __restrict__ a4,
    float* __restrict__ Wc) {
    __shared__ float rowbuf[4][64];
    int lane = threadIdx.x & 63;
    int w = threadIdx.x >> 6;
    int row = blockIdx.x * 4 + w;
    int h = row / CPH, c = row % CPH;
    float a = -INFINITY;
    if (lane < CPH) {
        float s = S[(h * CPH + c) * CPH + lane];
        float nq = fmaxf(sqrtf(fmaxf(qn[h * CPH + c], 0.f)), 1e-12f);
        float nk = fmaxf(sqrtf(fmaxf(kn[h * CPH + lane], 0.f)), 1e-12f);
        a = s / (nq * nk) * temp[h];
    }
    rowbuf[w][lane] = a;
    __syncthreads();
    int rank = 0;
    float m = -INFINITY;
    for (int j = 0; j < CPH; j++) {
        float vj = rowbuf[w][j];
        m = fmaxf(m, vj);
        rank += (vj > a || (vj == a && j < lane)) ? 1 : 0;
    }
    float e = (lane < CPH) ? expf(a - m) : 0.f;
    float4 p;
    p.x = (rank < 24) ? e : 0.f;
    p.y = (rank < 32) ? e : 0.f;
    p.z = (rank < 36) ? e : 0.f;
    p.w = (rank < 38) ? e : 0.f;
#pragma unroll
    for (int off = 32; off > 0; off >>= 1) {
        p.x += __shfl_xor(p.x, off);
        p.y += __shfl_xor(p.y, off);
        p.z += __shfl_xor(p.z, off);
        p.w += __shfl_xor(p.w, off);
    }
    if (lane < CPH) {
        float wv = 0.f;
        if (rank < 24) wv += a1[0] / p.x;
        if (rank < 32) wv += a2[0] / p.y;
        if (rank < 36) wv += a3[0] / p.z;
        if (rank < 38) wv += a4[0] / p.w;
        Wc[(h * CPH + c) * CPH + lane] = e * wv;
    }
}

// ---------------- K5: out96 = gelu( Wc @ v ) ---------------------------------
__global__ __launch_bounds__(256) void k_av_gelu(
    const float* __restrict__ qkv, const float* __restrict__ Wc,
    float* __restrict__ out96) {
    __shared__ float Wt[48][48];
    int tid = threadIdx.x;
    int h = blockIdx.y;
    int n = blockIdx.x * 512 + tid * 2;
#pragma unroll
    for (int it = 0; it < 9; it++) {
        int li = tid + 256 * it;
        if (li < 2304) {
            int dd = li / 48, cc = li - dd * 48;
            Wt[dd][cc] = Wc[(h * CPH + cc) * CPH + dd];
        }
    }
    __syncthreads();
    float2 acc[48];
#pragma unroll
    for (int c = 0; c < 48; c++) acc[c] = make_float2(0.f, 0.f);
    const float* vb = qkv + (size_t)(2 * D + h * CPH) * NP + n;
    for (int d = 0; d < 48; d++) {
        float2 vv = *(const float2*)&vb[(size_t)d * NP];
#pragma unroll
        for (int c4 = 0; c4 < 12; c4++) {
            float4 wv = *(const float4*)&Wt[d][c4 * 4];
            acc[c4 * 4 + 0].x += wv.x * vv.x; acc[c4 * 4 + 0].y += wv.x * vv.y;
            acc[c4 * 4 + 1].x += wv.y * vv.x; acc[c4 * 4 + 1].y += wv.y * vv.y;
            acc[c4 * 4 + 2].x += wv.z * vv.x; acc[c4 * 4 + 2].y += wv.z * vv.y;
            acc[c4 * 4 + 3].x += wv.w * vv.x; acc[c4 * 4 + 3].y += wv.w * vv.y;
        }
    }
#pragma unroll
    for (int c = 0; c < 48; c++) {
        float2 g = make_float2(gelu_exact(acc[c].x), gelu_exact(acc[c].y));
        *(float2*)&out96[(size_t)(h * CPH + c) * NP + n] = g;
    }
}

// ---------------- K6: proj 1x1 at 96x96 + nearest 2x upsample ----------------
__global__ __launch_bounds__(256) void k_proj_up(
    const float* __restrict__ out96, const float* __restrict__ wp,
    const float* __restrict__ bp, float* __restrict__ out) {
    __shared__ float Xs[32][64];
    __shared__ float Ws[32][68];
    int tid = threadIdx.x;
    int tx = tid & 15, ty = tid >> 4;
    int o0 = blockIdx.y * 64;
    int n0 = blockIdx.x * 64;
    float4 acc[4];
#pragma unroll
    for (int i = 0; i < 4; i++) acc[i] = make_float4(0.f, 0.f, 0.f, 0.f);
    for (int kc = 0; kc < D; kc += 32) {
        __syncthreads();
#pragma unroll
        for (int it = 0; it < 8; it++) {
            int li = tid + 256 * it;
            int col = li & 63, k = li >> 6;
            Xs[k][col] = out96[(size_t)(kc + k) * NP + n0 + col];
        }
#pragma unroll
        for (int it = 0; it < 8; it++) {
            int li = tid + 256 * it;
            int kk = li & 31, ol = li >> 5;
            Ws[kk][ol] = wp[(size_t)(o0 + ol) * D + kc + kk];
        }
        __syncthreads();
#pragma unroll
        for (int k = 0; k < 32; k++) {
            float4 xv = *(const float4*)&Xs[k][tx * 4];
            float4 wv = *(const float4*)&Ws[k][ty * 4];
            fma4(acc[0], wv.x, xv);
            fma4(acc[1], wv.y, xv);
            fma4(acc[2], wv.z, xv);
            fma4(acc[3], wv.w, xv);
        }
    }
#pragma unroll
    for (int i = 0; i < 4; i++) {
        int o = o0 + ty * 4 + i;
        float bias = bp[o];
        float vals[4] = {acc[i].x + bias, acc[i].y + bias, acc[i].z + bias, acc[i].w + bias};
#pragma unroll
        for (int j = 0; j < 4; j++) {
            int n = n0 + tx * 4 + j;
            int yy = n / WP, xx = n - yy * WP;
            size_t base = (size_t)o * NF + (size_t)(2 * yy) * WFULL + 2 * xx;
            float2 vv = make_float2(vals[j], vals[j]);
            *(float2*)&out[base] = vv;
            *(float2*)&out[base + WFULL] = vv;
        }
    }
}

extern "C" void kernel_launch(void* const* d_in, const int* in_sizes, int n_in,
                              void* d_out, int out_size, void* d_ws, size_t ws_size,
                              hipStream_t stream) {
    (void)in_sizes; (void)n_in; (void)out_size; (void)ws_size;
    const float* x    = (const float*)d_in[0];
    const float* wq   = (const float*)d_in[1];
    const float* bq   = (const float*)d_in[2];
    const float* wd   = (const float*)d_in[3];
    const float* bd   = (const float*)d_in[4];
    const float* wp   = (const float*)d_in[5];
    const float* bp   = (const float*)d_in[6];
    const float* temp = (const float*)d_in[7];
    const float* a1   = (const float*)d_in[8];
    const float* a2   = (const float*)d_in[9];
    const float* a3   = (const float*)d_in[10];
    const float* a4   = (const float*)d_in[11];
    float* out = (float*)d_out;
    float* ws  = (float*)d_ws;

    float* pooled = ws;                       // 10,616,832 floats
    float* S      = ws + 10616832;            // 18,432
    float* qn     = S + 18432;                // 384
    float* kn     = qn + 384;                 // 384
    float* Wc     = kn + 384;                 // 18,432
    ushort* wh    = (ushort*)(Wc + 18432);    // 442,368 bf16
    ushort* wl    = wh + 442368;              // 442,368 bf16
    float* out96  = pooled;                   // reuse (pooled dead after K2)
    float* qkvdw  = out;                      // q,k,v after dw conv staged in d_out

    // x split (bf16 hi/lo) staged in d_out; dead before dwconv overwrites it
    ushort* xh = (ushort*)d_out;              // 14,155,776 bf16
    ushort* xl = xh + 14155776;               // 14,155,776 bf16

    hipLaunchKernelGGL(k_zero,     dim3(75),        dim3(256), 0, stream, S, 19200);
    hipLaunchKernelGGL(k_prep_w,   dim3(1728),      dim3(256), 0, stream, wq, wh, wl, QC * D);
    hipLaunchKernelGGL(k_prep_x,   dim3(288, 6),    dim3(256), 0, stream, x, xh, xl);
    hipLaunchKernelGGL(k_qkv_mfma, dim3(2592),      dim3(256), 0, stream, xh, xl, wh, wl, bq, pooled);
    hipLaunchKernelGGL(k_dwconv,   dim3(41472),     dim3(256), 0, stream, pooled, wd, bd, qkvdw);
    hipLaunchKernelGGL(k_attn,     dim3(96, 8),     dim3(64),  0, stream, qkvdw, S, qn, kn);
    hipLaunchKernelGGL(k_softmax,  dim3(96),        dim3(256), 0, stream, S, qn, kn, temp, a1, a2, a3, a4, Wc);
    hipLaunchKernelGGL(k_av_gelu,  dim3(18, 8),     dim3(256), 0, stream, qkvdw, Wc, out96);
    hipLaunchKernelGGL(k_proj_up,  dim3(144, 6),    dim3(256), 0, stream, out96, wp, bp, out);
}

// Round 5
// 362.370 us; speedup vs baseline: 1.0278x; 1.0278x over previous
//
#include <hip/hip_runtime.h>
#include <hip/hip_bf16.h>
#include <math.h>

#define NH    8
#define CPH   48
#define D     384
#define QC    1152
#define HF    192
#define WFULL 192
#define HP    96
#define WP    96
#define NP    9216    // 96*96
#define NF    36864   // 192*192

typedef __attribute__((ext_vector_type(8))) short short8;
typedef __attribute__((ext_vector_type(4))) float f32x4;

__device__ __forceinline__ void fma4(float4& a, float s, const float4& v) {
    a.x += s * v.x; a.y += s * v.y; a.z += s * v.z; a.w += s * v.w;
}
__device__ __forceinline__ float gelu_exact(float v) {
    return 0.5f * v * (1.f + erff(v * 0.70710678118654752440f));
}
__device__ __forceinline__ ushort f2bf(float v) {
    __hip_bfloat16 h = __float2bfloat16(v);
    return *reinterpret_cast<ushort*>(&h);
}
__device__ __forceinline__ float bf2f(ushort u) {
    __hip_bfloat16 h = *reinterpret_cast<__hip_bfloat16*>(&u);
    return __bfloat162float(h);
}

__global__ void k_zero(float* p, int n) {
    int i = blockIdx.x * 256 + threadIdx.x;
    if (i < n) p[i] = 0.f;
}

// ---------------- P1: split w into bf16 hi/lo --------------------------------
__global__ __launch_bounds__(256) void k_prep_w(
    const float* __restrict__ w, ushort* __restrict__ wh, ushort* __restrict__ wl, int n) {
    int i = blockIdx.x * 256 + threadIdx.x;
    if (i < n) {
        float v = w[i];
        ushort h = f2bf(v);
        wh[i] = h;
        wl[i] = f2bf(v - bf2f(h));
    }
}

// ---------------- P2: split+transpose x -> [n'][c] bf16 hi/lo ---------------
// n' = (py*96+px)*4 + (y&1)*2 + (x&1)   (pool-quad-contiguous pixel order)
__global__ __launch_bounds__(256) void k_prep_x(
    const float* __restrict__ x, ushort* __restrict__ xh, ushort* __restrict__ xl) {
    __shared__ float xf[64][128];   // [ch][r*64+col], 32 KB
    const int tid = threadIdx.x;
    const int kk = blockIdx.y * 64;
    const int q0 = blockIdx.x * 32;          // 32 pool quads (one pool row chunk)
    const int py = q0 / 96, px0 = q0 - py * 96;
    const int y0 = 2 * py, xcol0 = 2 * px0;
    const float* xb = x + (size_t)kk * NF + (size_t)y0 * WFULL + xcol0;
#pragma unroll
    for (int it = 0; it < 8; it++) {
        int li = tid + 256 * it;
        int ch = li >> 5, r = (li >> 4) & 1, c4 = (li & 15) * 4;
        float4 v = *(const float4*)&xb[(size_t)ch * NF + r * WFULL + c4];
        *(float4*)&xf[ch][r * 64 + c4] = v;
    }
    __syncthreads();
    const int row = tid >> 1, half = tid & 1;
    const int r = (row >> 1) & 1;
    const int col = (row >> 2) * 2 + (row & 1);
    const int src = r * 64 + col;
    const size_t np = (size_t)blockIdx.x * 128 + row;
    ushort hbuf[32], lbuf[32];
#pragma unroll
    for (int j = 0; j < 32; j++) {
        float v = xf[half * 32 + j][src];
        ushort h = f2bf(v);
        hbuf[j] = h;
        lbuf[j] = f2bf(v - bf2f(h));
    }
    ushort* dh = xh + np * D + kk + half * 32;
    ushort* dl = xl + np * D + kk + half * 32;
#pragma unroll
    for (int j = 0; j < 4; j++) {
        *(short8*)&dh[j * 8] = *(const short8*)&hbuf[j * 8];
        *(short8*)&dl[j * 8] = *(const short8*)&lbuf[j * 8];
    }
}

// ---------------- K1: qkv 1x1 conv as bf16x3 MFMA GEMM + fused 2x2 maxpool ---
// C[n', o] = sum_k x'[n',k] w[o,k];  M=36864(n'), N=1152(o), K=384
// 128x128 tile, BK=32, 4 waves, 2-bit XOR-swizzled LDS, global_load_lds,
// XCD-aware remap.  R5: double-buffered LDS + counted vmcnt(8) pipeline
// (T3-minimum + T4): next K-step's loads stay in flight across the barrier.
__global__ __launch_bounds__(256) void k_qkv_mfma(
    const ushort* __restrict__ xh, const ushort* __restrict__ xl,
    const ushort* __restrict__ wh, const ushort* __restrict__ wl,
    const float* __restrict__ bq, float* __restrict__ pooled) {
    __shared__ ushort lds[2][4][4096];  // [buf][Ah,Al,Bh,Bl][128 rows x 32 bf16]
    const int tid = threadIdx.x;
    const int lane = tid & 63, wid = tid >> 6;
    const int wm = wid >> 1, wn = wid & 1;

    const int d   = blockIdx.x;        // 0..2591, HW XCD = d % 8
    const int xcd = d & 7;
    const int idx = d >> 3;
    const int by  = xcd * 36 + idx / 9;
    const int bx  = idx % 9;
    const int n0 = bx * 128;
    const int m0 = by * 128;

    const ushort* srcs[4];
    srcs[0] = xh + (size_t)m0 * D;
    srcs[1] = xl + (size_t)m0 * D;
    srcs[2] = wh + (size_t)n0 * D;
    srcs[3] = wl + (size_t)n0 * D;

    f32x4 acc[4][4];
#pragma unroll
    for (int i = 0; i < 4; i++)
#pragma unroll
        for (int j = 0; j < 4; j++) acc[i][j] = (f32x4){0.f, 0.f, 0.f, 0.f};

    // fragment ds_read byte offsets within one 8KB tile, 2-bit chunk XOR swizzle
    int a_off[4], b_off[4];
#pragma unroll
    for (int f = 0; f < 4; f++) {
        int ra = wm * 64 + f * 16 + (lane & 15);
        a_off[f] = ra * 64 + ((((lane >> 4) ^ ((ra >> 1) & 3)) & 3) << 4);
        int rb = wn * 64 + f * 16 + (lane & 15);
        b_off[f] = rb * 64 + ((((lane >> 4) ^ ((rb >> 1) & 3)) & 3) << 4);
    }

    // async stage of one 32KB K-step tile into buffer `buf`
    auto STAGE = [&](int buf, int kk) {
#pragma unroll
        for (int i = 0; i < 8; i++) {
            const int mat = i >> 1;
            const int cm  = ((i & 1) << 2) | wid;
            const int row = cm * 16 + (lane >> 2);
            const int scol = (((lane & 3) ^ ((row >> 1) & 3)) & 3) << 4;
            const ushort* src = srcs[mat] + (size_t)row * D + kk + (scol >> 1);
            __builtin_amdgcn_global_load_lds(
                (const __attribute__((address_space(1))) void*)src,
                (__attribute__((address_space(3))) void*)&lds[buf][mat][cm * 512],
                16, 0, 0);
        }
    };

    STAGE(0, 0);
    for (int t = 0; t < 12; ++t) {
        const int cur = t & 1;
        if (t < 11) {
            STAGE(cur ^ 1, (t + 1) * 32);
            asm volatile("s_waitcnt vmcnt(8)" ::: "memory");  // tile t landed
        } else {
            asm volatile("s_waitcnt vmcnt(0)" ::: "memory");
        }
        __builtin_amdgcn_s_barrier();

        const char* bA0 = (const char*)&lds[cur][0][0];
        const char* bA1 = (const char*)&lds[cur][1][0];
        const char* bB0 = (const char*)&lds[cur][2][0];
        const char* bB1 = (const char*)&lds[cur][3][0];
        short8 A[2][4], B[2][4];
#pragma unroll
        for (int f = 0; f < 4; f++) {
            A[0][f] = *(const short8*)(bA0 + a_off[f]);
            A[1][f] = *(const short8*)(bA1 + a_off[f]);
            B[0][f] = *(const short8*)(bB0 + b_off[f]);
            B[1][f] = *(const short8*)(bB1 + b_off[f]);
        }
        __builtin_amdgcn_s_setprio(1);
#pragma unroll
        for (int fm = 0; fm < 4; fm++)
#pragma unroll
            for (int fn = 0; fn < 4; fn++) {
                acc[fm][fn] = __builtin_amdgcn_mfma_f32_16x16x32_bf16(A[0][fm], B[0][fn], acc[fm][fn], 0, 0, 0);
                acc[fm][fn] = __builtin_amdgcn_mfma_f32_16x16x32_bf16(A[0][fm], B[1][fn], acc[fm][fn], 0, 0, 0);
                acc[fm][fn] = __builtin_amdgcn_mfma_f32_16x16x32_bf16(A[1][fm], B[0][fn], acc[fm][fn], 0, 0, 0);
            }
        __builtin_amdgcn_s_setprio(0);
        // all ds_read data in regs before next STAGE overwrites buf[cur^1... (t+1: cur)
        asm volatile("s_waitcnt lgkmcnt(0)" ::: "memory");
        __builtin_amdgcn_s_barrier();
    }

    const int p_base = by * 32 + wm * 16 + (lane >> 4);
#pragma unroll
    for (int fn = 0; fn < 4; fn++) {
        const int o = n0 + wn * 64 + fn * 16 + (lane & 15);
        const float b = bq[o];
#pragma unroll
        for (int fm = 0; fm < 4; fm++) {
            f32x4 v = acc[fm][fn];
            float mx = fmaxf(fmaxf(v.x, v.y), fmaxf(v.z, v.w)) + b;
            pooled[(size_t)o * NP + p_base + fm * 4] = mx;
        }
    }
}

// ---------------- K2: depthwise 3x3 conv, SAME padding -----------------------
__global__ __launch_bounds__(256) void k_dwconv(
    const float* __restrict__ pooled, const float* __restrict__ wd,
    const float* __restrict__ bd, float* __restrict__ out) {
    int gid = blockIdx.x * 256 + threadIdx.x;
    int ch = gid / NP;
    int n  = gid - ch * NP;
    int y  = n / WP;
    int x0 = n - y * WP;
    const float* src = pooled + (size_t)ch * NP;
    const float* w = wd + ch * 9;
    float s = bd[ch];
#pragma unroll
    for (int dy = 0; dy < 3; dy++) {
        int yy = y + dy - 1;
        if (yy < 0 || yy >= HP) continue;
#pragma unroll
        for (int dx = 0; dx < 3; dx++) {
            int xx = x0 + dx - 1;
            if (xx < 0 || xx >= WP) continue;
            s += src[yy * WP + xx] * w[dy * 3 + dx];
        }
    }
    out[gid] = s;
}

// ---------------- K3: attn partials S = q.k^T, plus sq-norms -----------------
__global__ __launch_bounds__(64) void k_attn(
    const float* __restrict__ qkv, float* __restrict__ S,
    float* __restrict__ qn, float* __restrict__ kn) {
    __shared__ float qs[48][97], ks[48][97];
    int t = threadIdx.x;
    int head = blockIdx.y;
    int n0 = blockIdx.x * 96;
    const float* qb = qkv + (size_t)(head * CPH) * NP + n0;
    const float* kb = qkv + (size_t)(D + head * CPH) * NP + n0;
    for (int it = 0; it < 72; it++) {
        int li = t + 64 * it;
        int col = li % 96, row = li / 96;
        qs[row][col] = qb[(size_t)row * NP + col];
        ks[row][col] = kb[(size_t)row * NP + col];
    }
    __syncthreads();
    int tr = t >> 3, tc = t & 7;
    float acc[6][6] = {};
    for (int n = 0; n < 96; n++) {
        float qv[6], kv[6];
#pragma unroll
        for (int i = 0; i < 6; i++) qv[i] = qs[tr * 6 + i][n];
#pragma unroll
        for (int j = 0; j < 6; j++) kv[j] = ks[tc * 6 + j][n];
#pragma unroll
        for (int i = 0; i < 6; i++)
#pragma unroll
            for (int j = 0; j < 6; j++) acc[i][j] += qv[i] * kv[j];
    }
    if (t < 48) {
        float sq = 0.f, sk = 0.f;
        for (int n = 0; n < 96; n++) {
            sq += qs[t][n] * qs[t][n];
            sk += ks[t][n] * ks[t][n];
        }
        atomicAdd(&qn[head * CPH + t], sq);
        atomicAdd(&kn[head * CPH + t], sk);
    }
    float* Sh = S + head * CPH * CPH;
#pragma unroll
    for (int i = 0; i < 6; i++)
#pragma unroll
        for (int j = 0; j < 6; j++)
            atomicAdd(&Sh[(tr * 6 + i) * CPH + tc * 6 + j], acc[i][j]);
}

// ---------------- K4: normalize + 4x nested top-k softmax --------------------
__global__ __launch_bounds__(256) void k_softmax(
    const float* __restrict__ S, const float* __restrict__ qn,
    const float* __restrict__ kn, const float* __restrict__ temp,
    const float* __restrict__ a1, const float* __restrict__ a2,
    const float* __restrict__ a3, const float* __restrict__ a4,
    float* __restrict__ Wc) {
    __shared__ float rowbuf[4][64];
    int lane = threadIdx.x & 63;
    int w = threadIdx.x >> 6;
    int row = blockIdx.x * 4 + w;
    int h = row / CPH, c = row % CPH;
    float a = -INFINITY;
    if (lane < CPH) {
        float s = S[(h * CPH + c) * CPH + lane];
        float nq = fmaxf(sqrtf(fmaxf(qn[h * CPH + c], 0.f)), 1e-12f);
        float nk = fmaxf(sqrtf(fmaxf(kn[h * CPH + lane], 0.f)), 1e-12f);
        a = s / (nq * nk) * temp[h];
    }
    rowbuf[w][lane] = a;
    __syncthreads();
    int rank = 0;
    float m = -INFINITY;
    for (int j = 0; j < CPH; j++) {
        float vj = rowbuf[w][j];
        m = fmaxf(m, vj);
        rank += (vj > a || (vj == a && j < lane)) ? 1 : 0;
    }
    float e = (lane < CPH) ? expf(a - m) : 0.f;
    float4 p;
    p.x = (rank < 24) ? e : 0.f;
    p.y = (rank < 32) ? e : 0.f;
    p.z = (rank < 36) ? e : 0.f;
    p.w = (rank < 38) ? e : 0.f;
#pragma unroll
    for (int off = 32; off > 0; off >>= 1) {
        p.x += __shfl_xor(p.x, off);
        p.y += __shfl_xor(p.y, off);
        p.z += __shfl_xor(p.z, off);
        p.w += __shfl_xor(p.w, off);
    }
    if (lane < CPH) {
        float wv = 0.f;
        if (rank < 24) wv += a1[0] / p.x;
        if (rank < 32) wv += a2[0] / p.y;
        if (rank < 36) wv += a3[0] / p.z;
        if (rank < 38) wv += a4[0] / p.w;
        Wc[(h * CPH + c) * CPH + lane] = e * wv;
    }
}

// ---------------- K5: out96 = gelu( Wc @ v ) ---------------------------------
__global__ __launch_bounds__(256) void k_av_gelu(
    const float* __restrict__ qkv, const float* __restrict__ Wc,
    float* __restrict__ out96) {
    __shared__ float Wt[48][48];
    int tid = threadIdx.x;
    int h = blockIdx.y;
    int n = blockIdx.x * 512 + tid * 2;
#pragma unroll
    for (int it = 0; it < 9; it++) {
        int li = tid + 256 * it;
        if (li < 2304) {
            int dd = li / 48, cc = li - dd * 48;
            Wt[dd][cc] = Wc[(h * CPH + cc) * CPH + dd];
        }
    }
    __syncthreads();
    float2 acc[48];
#pragma unroll
    for (int c = 0; c < 48; c++) acc[c] = make_float2(0.f, 0.f);
    const float* vb = qkv + (size_t)(2 * D + h * CPH) * NP + n;
    for (int d = 0; d < 48; d++) {
        float2 vv = *(const float2*)&vb[(size_t)d * NP];
#pragma unroll
        for (int c4 = 0; c4 < 12; c4++) {
            float4 wv = *(const float4*)&Wt[d][c4 * 4];
            acc[c4 * 4 + 0].x += wv.x * vv.x; acc[c4 * 4 + 0].y += wv.x * vv.y;
            acc[c4 * 4 + 1].x += wv.y * vv.x; acc[c4 * 4 + 1].y += wv.y * vv.y;
            acc[c4 * 4 + 2].x += wv.z * vv.x; acc[c4 * 4 + 2].y += wv.z * vv.y;
            acc[c4 * 4 + 3].x += wv.w * vv.x; acc[c4 * 4 + 3].y += wv.w * vv.y;
        }
    }
#pragma unroll
    for (int c = 0; c < 48; c++) {
        float2 g = make_float2(gelu_exact(acc[c].x), gelu_exact(acc[c].y));
        *(float2*)&out96[(size_t)(h * CPH + c) * NP + n] = g;
    }
}

// ---------------- K6: proj 1x1 at 96x96 + nearest 2x upsample ----------------
__global__ __launch_bounds__(256) void k_proj_up(
    const float* __restrict__ out96, const float* __restrict__ wp,
    const float* __restrict__ bp, float* __restrict__ out) {
    __shared__ float Xs[32][64];
    __shared__ float Ws[32][68];
    int tid = threadIdx.x;
    int tx = tid & 15, ty = tid >> 4;
    int o0 = blockIdx.y * 64;
    int n0 = blockIdx.x * 64;
    float4 acc[4];
#pragma unroll
    for (int i = 0; i < 4; i++) acc[i] = make_float4(0.f, 0.f, 0.f, 0.f);
    for (int kc = 0; kc < D; kc += 32) {
        __syncthreads();
#pragma unroll
        for (int it = 0; it < 8; it++) {
            int li = tid + 256 * it;
            int col = li & 63, k = li >> 6;
            Xs[k][col] = out96[(size_t)(kc + k) * NP + n0 + col];
        }
#pragma unroll
        for (int it = 0; it < 8; it++) {
            int li = tid + 256 * it;
            int kk = li & 31, ol = li >> 5;
            Ws[kk][ol] = wp[(size_t)(o0 + ol) * D + kc + kk];
        }
        __syncthreads();
#pragma unroll
        for (int k = 0; k < 32; k++) {
            float4 xv = *(const float4*)&Xs[k][tx * 4];
            float4 wv = *(const float4*)&Ws[k][ty * 4];
            fma4(acc[0], wv.x, xv);
            fma4(acc[1], wv.y, xv);
            fma4(acc[2], wv.z, xv);
            fma4(acc[3], wv.w, xv);
        }
    }
#pragma unroll
    for (int i = 0; i < 4; i++) {
        int o = o0 + ty * 4 + i;
        float bias = bp[o];
        float vals[4] = {acc[i].x + bias, acc[i].y + bias, acc[i].z + bias, acc[i].w + bias};
#pragma unroll
        for (int j = 0; j < 4; j++) {
            int n = n0 + tx * 4 + j;
            int yy = n / WP, xx = n - yy * WP;
            size_t base = (size_t)o * NF + (size_t)(2 * yy) * WFULL + 2 * xx;
            float2 vv = make_float2(vals[j], vals[j]);
            *(float2*)&out[base] = vv;
            *(float2*)&out[base + WFULL] = vv;
        }
    }
}

extern "C" void kernel_launch(void* const* d_in, const int* in_sizes, int n_in,
                              void* d_out, int out_size, void* d_ws, size_t ws_size,
                              hipStream_t stream) {
    (void)in_sizes; (void)n_in; (void)out_size; (void)ws_size;
    const float* x    = (const float*)d_in[0];
    const float* wq   = (const float*)d_in[1];
    const float* bq   = (const float*)d_in[2];
    const float* wd   = (const float*)d_in[3];
    const float* bd   = (const float*)d_in[4];
    const float* wp   = (const float*)d_in[5];
    const float* bp   = (const float*)d_in[6];
    const float* temp = (const float*)d_in[7];
    const float* a1   = (const float*)d_in[8];
    const float* a2   = (const float*)d_in[9];
    const float* a3   = (const float*)d_in[10];
    const float* a4   = (const float*)d_in[11];
    float* out = (float*)d_out;
    float* ws  = (float*)d_ws;

    float* pooled = ws;                       // 10,616,832 floats
    float* S      = ws + 10616832;            // 18,432
    float* qn     = S + 18432;                // 384
    float* kn     = qn + 384;                 // 384
    float* Wc     = kn + 384;                 // 18,432
    ushort* wh    = (ushort*)(Wc + 18432);    // 442,368 bf16
    ushort* wl    = wh + 442368;              // 442,368 bf16
    float* out96  = pooled;                   // reuse (pooled dead after K2)
    float* qkvdw  = out;                      // q,k,v after dw conv staged in d_out

    // x split (bf16 hi/lo) staged in d_out; dead before dwconv overwrites it
    ushort* xh = (ushort*)d_out;              // 14,155,776 bf16
    ushort* xl = xh + 14155776;               // 14,155,776 bf16

    hipLaunchKernelGGL(k_zero,     dim3(75),        dim3(256), 0, stream, S, 19200);
    hipLaunchKernelGGL(k_prep_w,   dim3(1728),      dim3(256), 0, stream, wq, wh, wl, QC * D);
    hipLaunchKernelGGL(k_prep_x,   dim3(288, 6),    dim3(256), 0, stream, x, xh, xl);
    hipLaunchKernelGGL(k_qkv_mfma, dim3(2592),      dim3(256), 0, stream, xh, xl, wh, wl, bq, pooled);
    hipLaunchKernelGGL(k_dwconv,   dim3(41472),     dim3(256), 0, stream, pooled, wd, bd, qkvdw);
    hipLaunchKernelGGL(k_attn,     dim3(96, 8),     dim3(64),  0, stream, qkvdw, S, qn, kn);
    hipLaunchKernelGGL(k_softmax,  dim3(96),        dim3(256), 0, stream, S, qn, kn, temp, a1, a2, a3, a4, Wc);
    hipLaunchKernelGGL(k_av_gelu,  dim3(18, 8),     dim3(256), 0, stream, qkvdw, Wc, out96);
    hipLaunchKernelGGL(k_proj_up,  dim3(144, 6),    dim3(256), 0, stream, out96, wp, bp, out);
}

// Round 6
// 277.798 us; speedup vs baseline: 1.3407x; 1.3044x over previous
//
#include <hip/hip_runtime.h>
#include <hip/hip_bf16.h>
#include <math.h>

#define NH    8
#define CPH   48
#define D     384
#define QC    1152
#define HF    192
#define WFULL 192
#define HP    96
#define WP    96
#define NP    9216    // 96*96
#define NF    36864   // 192*192

typedef __attribute__((ext_vector_type(8))) short short8;
typedef __attribute__((ext_vector_type(4))) float f32x4;

__device__ __forceinline__ float gelu_exact(float v) {
    return 0.5f * v * (1.f + erff(v * 0.70710678118654752440f));
}
__device__ __forceinline__ ushort f2bf(float v) {
    __hip_bfloat16 h = __float2bfloat16(v);
    return *reinterpret_cast<ushort*>(&h);
}
__device__ __forceinline__ float bf2f(ushort u) {
    __hip_bfloat16 h = *reinterpret_cast<__hip_bfloat16*>(&u);
    return __bfloat162float(h);
}

// ---------------- P1: split fp32 -> bf16 hi/lo (used for wq and wp) ----------
__global__ __launch_bounds__(256) void k_prep_w(
    const float* __restrict__ w, ushort* __restrict__ wh, ushort* __restrict__ wl, int n) {
    int i = blockIdx.x * 256 + threadIdx.x;
    if (i < n) {
        float v = w[i];
        ushort h = f2bf(v);
        wh[i] = h;
        wl[i] = f2bf(v - bf2f(h));
    }
}

// ---------------- P2: split+transpose x -> [n'][c] bf16 hi/lo ---------------
// n' = (py*96+px)*4 + (y&1)*2 + (x&1)   (pool-quad-contiguous pixel order)
__global__ __launch_bounds__(256) void k_prep_x(
    const float* __restrict__ x, ushort* __restrict__ xh, ushort* __restrict__ xl) {
    __shared__ float xf[64][128];   // [ch][r*64+col], 32 KB
    const int tid = threadIdx.x;
    const int kk = blockIdx.y * 64;
    const int q0 = blockIdx.x * 32;          // 32 pool quads (one pool row chunk)
    const int py = q0 / 96, px0 = q0 - py * 96;
    const int y0 = 2 * py, xcol0 = 2 * px0;
    const float* xb = x + (size_t)kk * NF + (size_t)y0 * WFULL + xcol0;
#pragma unroll
    for (int it = 0; it < 8; it++) {
        int li = tid + 256 * it;
        int ch = li >> 5, r = (li >> 4) & 1, c4 = (li & 15) * 4;
        float4 v = *(const float4*)&xb[(size_t)ch * NF + r * WFULL + c4];
        *(float4*)&xf[ch][r * 64 + c4] = v;
    }
    __syncthreads();
    const int row = tid >> 1, half = tid & 1;
    const int r = (row >> 1) & 1;
    const int col = (row >> 2) * 2 + (row & 1);
    const int src = r * 64 + col;
    const size_t np = (size_t)blockIdx.x * 128 + row;
    ushort hbuf[32], lbuf[32];
#pragma unroll
    for (int j = 0; j < 32; j++) {
        float v = xf[half * 32 + j][src];
        ushort h = f2bf(v);
        hbuf[j] = h;
        lbuf[j] = f2bf(v - bf2f(h));
    }
    ushort* dh = xh + np * D + kk + half * 32;
    ushort* dl = xl + np * D + kk + half * 32;
#pragma unroll
    for (int j = 0; j < 4; j++) {
        *(short8*)&dh[j * 8] = *(const short8*)&hbuf[j * 8];
        *(short8*)&dl[j * 8] = *(const short8*)&lbuf[j * 8];
    }
}

// ---------------- K1: qkv 1x1 conv as bf16x3 MFMA GEMM + fused 2x2 maxpool ---
// C[n', o] = sum_k x'[n',k] w[o,k];  M=36864(n'), N=1152(o), K=384
// 128x128 tile, BK=32, double-buffered LDS + counted vmcnt pipeline.
__global__ __launch_bounds__(256) void k_qkv_mfma(
    const ushort* __restrict__ xh, const ushort* __restrict__ xl,
    const ushort* __restrict__ wh, const ushort* __restrict__ wl,
    const float* __restrict__ bq, float* __restrict__ pooled) {
    __shared__ ushort lds[2][4][4096];  // [buf][Ah,Al,Bh,Bl][128 rows x 32 bf16]
    const int tid = threadIdx.x;
    const int lane = tid & 63, wid = tid >> 6;
    const int wm = wid >> 1, wn = wid & 1;

    const int d   = blockIdx.x;        // 0..2591, HW XCD = d % 8
    const int xcd = d & 7;
    const int idx = d >> 3;
    const int by  = xcd * 36 + idx / 9;
    const int bx  = idx % 9;
    const int n0 = bx * 128;
    const int m0 = by * 128;

    const ushort* srcs[4];
    srcs[0] = xh + (size_t)m0 * D;
    srcs[1] = xl + (size_t)m0 * D;
    srcs[2] = wh + (size_t)n0 * D;
    srcs[3] = wl + (size_t)n0 * D;

    f32x4 acc[4][4];
#pragma unroll
    for (int i = 0; i < 4; i++)
#pragma unroll
        for (int j = 0; j < 4; j++) acc[i][j] = (f32x4){0.f, 0.f, 0.f, 0.f};

    int a_off[4], b_off[4];
#pragma unroll
    for (int f = 0; f < 4; f++) {
        int ra = wm * 64 + f * 16 + (lane & 15);
        a_off[f] = ra * 64 + ((((lane >> 4) ^ ((ra >> 1) & 3)) & 3) << 4);
        int rb = wn * 64 + f * 16 + (lane & 15);
        b_off[f] = rb * 64 + ((((lane >> 4) ^ ((rb >> 1) & 3)) & 3) << 4);
    }

    auto STAGE = [&](int buf, int kk) {
#pragma unroll
        for (int i = 0; i < 8; i++) {
            const int mat = i >> 1;
            const int cm  = ((i & 1) << 2) | wid;
            const int row = cm * 16 + (lane >> 2);
            const int scol = (((lane & 3) ^ ((row >> 1) & 3)) & 3) << 4;
            const ushort* src = srcs[mat] + (size_t)row * D + kk + (scol >> 1);
            __builtin_amdgcn_global_load_lds(
                (const __attribute__((address_space(1))) void*)src,
                (__attribute__((address_space(3))) void*)&lds[buf][mat][cm * 512],
                16, 0, 0);
        }
    };

    STAGE(0, 0);
    for (int t = 0; t < 12; ++t) {
        const int cur = t & 1;
        if (t < 11) {
            STAGE(cur ^ 1, (t + 1) * 32);
            asm volatile("s_waitcnt vmcnt(8)" ::: "memory");
        } else {
            asm volatile("s_waitcnt vmcnt(0)" ::: "memory");
        }
        __builtin_amdgcn_s_barrier();

        const char* bA0 = (const char*)&lds[cur][0][0];
        const char* bA1 = (const char*)&lds[cur][1][0];
        const char* bB0 = (const char*)&lds[cur][2][0];
        const char* bB1 = (const char*)&lds[cur][3][0];
        short8 A[2][4], B[2][4];
#pragma unroll
        for (int f = 0; f < 4; f++) {
            A[0][f] = *(const short8*)(bA0 + a_off[f]);
            A[1][f] = *(const short8*)(bA1 + a_off[f]);
            B[0][f] = *(const short8*)(bB0 + b_off[f]);
            B[1][f] = *(const short8*)(bB1 + b_off[f]);
        }
        __builtin_amdgcn_s_setprio(1);
#pragma unroll
        for (int fm = 0; fm < 4; fm++)
#pragma unroll
            for (int fn = 0; fn < 4; fn++) {
                acc[fm][fn] = __builtin_amdgcn_mfma_f32_16x16x32_bf16(A[0][fm], B[0][fn], acc[fm][fn], 0, 0, 0);
                acc[fm][fn] = __builtin_amdgcn_mfma_f32_16x16x32_bf16(A[0][fm], B[1][fn], acc[fm][fn], 0, 0, 0);
                acc[fm][fn] = __builtin_amdgcn_mfma_f32_16x16x32_bf16(A[1][fm], B[0][fn], acc[fm][fn], 0, 0, 0);
            }
        __builtin_amdgcn_s_setprio(0);
        asm volatile("s_waitcnt lgkmcnt(0)" ::: "memory");
        __builtin_amdgcn_s_barrier();
    }

    const int p_base = by * 32 + wm * 16 + (lane >> 4);
#pragma unroll
    for (int fn = 0; fn < 4; fn++) {
        const int o = n0 + wn * 64 + fn * 16 + (lane & 15);
        const float b = bq[o];
#pragma unroll
        for (int fm = 0; fm < 4; fm++) {
            f32x4 v = acc[fm][fn];
            float mx = fmaxf(fmaxf(v.x, v.y), fmaxf(v.z, v.w)) + b;
            pooled[(size_t)o * NP + p_base + fm * 4] = mx;
        }
    }
}

// ---------------- K2: depthwise 3x3 conv, SAME padding -----------------------
__global__ __launch_bounds__(256) void k_dwconv(
    const float* __restrict__ pooled, const float* __restrict__ wd,
    const float* __restrict__ bd, float* __restrict__ out) {
    int gid = blockIdx.x * 256 + threadIdx.x;
    int ch = gid / NP;
    int n  = gid - ch * NP;
    int y  = n / WP;
    int x0 = n - y * WP;
    const float* src = pooled + (size_t)ch * NP;
    const float* w = wd + ch * 9;
    float s = bd[ch];
#pragma unroll
    for (int dy = 0; dy < 3; dy++) {
        int yy = y + dy - 1;
        if (yy < 0 || yy >= HP) continue;
#pragma unroll
        for (int dx = 0; dx < 3; dx++) {
            int xx = x0 + dx - 1;
            if (xx < 0 || xx >= WP) continue;
            s += src[yy * WP + xx] * w[dy * 3 + dx];
        }
    }
    out[gid] = s;
}

// ---------------- K3a: attn partials, no atomics -----------------------------
// grid (48 chunks of 192, 8 heads), 256 thr. Writes private Spart/qnpart/knpart.
__global__ __launch_bounds__(256) void k_attn_part(
    const float* __restrict__ qkv, float* __restrict__ Spart,
    float* __restrict__ qnpart, float* __restrict__ knpart) {
    __shared__ float qs[48][196], ks[48][196];
    const int tid = threadIdx.x;
    const int p = blockIdx.x, h = blockIdx.y;
    const int n0 = p * 192;
    const float* qb = qkv + (size_t)(h * CPH) * NP + n0;
    const float* kb = qkv + (size_t)(D + h * CPH) * NP + n0;
#pragma unroll
    for (int it = 0; it < 9; it++) {
        int li = tid + 256 * it;             // 0..2303 float4s
        int row = li / 48, c4 = (li - row * 48) * 4;
        *(float4*)&qs[row][c4] = *(const float4*)&qb[(size_t)row * NP + c4];
        *(float4*)&ks[row][c4] = *(const float4*)&kb[(size_t)row * NP + c4];
    }
    __syncthreads();
    const int tr = (tid >> 4) * 3, tc = (tid & 15) * 3;
    float acc[3][3] = {};
    for (int n = 0; n < 192; n++) {
        float qv[3], kv[3];
#pragma unroll
        for (int i = 0; i < 3; i++) qv[i] = qs[tr + i][n];
#pragma unroll
        for (int j = 0; j < 3; j++) kv[j] = ks[tc + j][n];
#pragma unroll
        for (int i = 0; i < 3; i++)
#pragma unroll
            for (int j = 0; j < 3; j++) acc[i][j] += qv[i] * kv[j];
    }
    float* Sp = Spart + (size_t)(p * NH + h) * 2304;
#pragma unroll
    for (int i = 0; i < 3; i++)
#pragma unroll
        for (int j = 0; j < 3; j++)
            Sp[(tr + i) * CPH + tc + j] = acc[i][j];
    if (tid < 48) {
        float s = 0.f;
        for (int n = 0; n < 192; n++) s += qs[tid][n] * qs[tid][n];
        qnpart[(p * NH + h) * CPH + tid] = s;
    } else if (tid >= 64 && tid < 112) {
        int t2 = tid - 64;
        float s = 0.f;
        for (int n = 0; n < 192; n++) s += ks[t2][n] * ks[t2][n];
        knpart[(p * NH + h) * CPH + t2] = s;
    }
}

// ---------------- K3b: reduce 48 partials -> S, qn, kn -----------------------
__global__ __launch_bounds__(256) void k_red(
    const float* __restrict__ Spart, const float* __restrict__ qnpart,
    const float* __restrict__ knpart, float* __restrict__ S,
    float* __restrict__ qn, float* __restrict__ kn) {
    int gid = blockIdx.x * 256 + threadIdx.x;   // 0..19199
    if (gid < 18432) {
        int h = gid / 2304, ij = gid - h * 2304;
        float s = 0.f;
        for (int ppp = 0; ppp < 48; ppp++) s += Spart[(size_t)(ppp * NH + h) * 2304 + ij];
        S[gid] = s;
    } else if (gid < 18816) {
        int i = gid - 18432;                     // h*48+c
        int h = i / CPH, c = i - h * CPH;
        float s = 0.f;
        for (int ppp = 0; ppp < 48; ppp++) s += qnpart[(ppp * NH + h) * CPH + c];
        qn[i] = s;
    } else {
        int i = gid - 18816;
        int h = i / CPH, c = i - h * CPH;
        float s = 0.f;
        for (int ppp = 0; ppp < 48; ppp++) s += knpart[(ppp * NH + h) * CPH + c];
        kn[i] = s;
    }
}

// ---------------- K4: normalize + 4x nested top-k softmax --------------------
__global__ __launch_bounds__(256) void k_softmax(
    const float* __restrict__ S, const float* __restrict__ qn,
    const float* __restrict__ kn, const float* __restrict__ temp,
    const float* __restrict__ a1, const float* __restrict__ a2,
    const float* __restrict__ a3, const float* __restrict__ a4,
    float* __restrict__ Wc) {
    __shared__ float rowbuf[4][64];
    int lane = threadIdx.x & 63;
    int w = threadIdx.x >> 6;
    int row = blockIdx.x * 4 + w;
    int h = row / CPH, c = row % CPH;
    float a = -INFINITY;
    if (lane < CPH) {
        float s = S[(h * CPH + c) * CPH + lane];
        float nq = fmaxf(sqrtf(fmaxf(qn[h * CPH + c], 0.f)), 1e-12f);
        float nk = fmaxf(sqrtf(fmaxf(kn[h * CPH + lane], 0.f)), 1e-12f);
        a = s / (nq * nk) * temp[h];
    }
    rowbuf[w][lane] = a;
    __syncthreads();
    int rank = 0;
    float m = -INFINITY;
    for (int j = 0; j < CPH; j++) {
        float vj = rowbuf[w][j];
        m = fmaxf(m, vj);
        rank += (vj > a || (vj == a && j < lane)) ? 1 : 0;
    }
    float e = (lane < CPH) ? expf(a - m) : 0.f;
    float4 p;
    p.x = (rank < 24) ? e : 0.f;
    p.y = (rank < 32) ? e : 0.f;
    p.z = (rank < 36) ? e : 0.f;
    p.w = (rank < 38) ? e : 0.f;
#pragma unroll
    for (int off = 32; off > 0; off >>= 1) {
        p.x += __shfl_xor(p.x, off);
        p.y += __shfl_xor(p.y, off);
        p.z += __shfl_xor(p.z, off);
        p.w += __shfl_xor(p.w, off);
    }
    if (lane < CPH) {
        float wv = 0.f;
        if (rank < 24) wv += a1[0] / p.x;
        if (rank < 32) wv += a2[0] / p.y;
        if (rank < 36) wv += a3[0] / p.z;
        if (rank < 38) wv += a4[0] / p.w;
        Wc[(h * CPH + c) * CPH + lane] = e * wv;
    }
}

// ---------------- K5: gelu(Wc @ v) -> bf16 hi/lo rows [n][384] ---------------
__global__ __launch_bounds__(256) void k_av_gelu(
    const float* __restrict__ qkv, const float* __restrict__ Wc,
    ushort* __restrict__ o96h, ushort* __restrict__ o96l) {
    __shared__ float Wt[48][48];
    int tid = threadIdx.x;
    int h = blockIdx.y;
    int n = blockIdx.x * 512 + tid * 2;
#pragma unroll
    for (int it = 0; it < 9; it++) {
        int li = tid + 256 * it;
        if (li < 2304) {
            int dd = li / 48, cc = li - dd * 48;
            Wt[dd][cc] = Wc[(h * CPH + cc) * CPH + dd];
        }
    }
    __syncthreads();
    float2 acc[48];
#pragma unroll
    for (int c = 0; c < 48; c++) acc[c] = make_float2(0.f, 0.f);
    const float* vb = qkv + (size_t)(2 * D + h * CPH) * NP + n;
    for (int d = 0; d < 48; d++) {
        float2 vv = *(const float2*)&vb[(size_t)d * NP];
#pragma unroll
        for (int c4 = 0; c4 < 12; c4++) {
            float4 wv = *(const float4*)&Wt[d][c4 * 4];
            acc[c4 * 4 + 0].x += wv.x * vv.x; acc[c4 * 4 + 0].y += wv.x * vv.y;
            acc[c4 * 4 + 1].x += wv.y * vv.x; acc[c4 * 4 + 1].y += wv.y * vv.y;
            acc[c4 * 4 + 2].x += wv.z * vv.x; acc[c4 * 4 + 2].y += wv.z * vv.y;
            acc[c4 * 4 + 3].x += wv.w * vv.x; acc[c4 * 4 + 3].y += wv.w * vv.y;
        }
    }
#pragma unroll
    for (int c8 = 0; c8 < 6; c8++) {
        short8 h0, l0, h1, l1;
#pragma unroll
        for (int e = 0; e < 8; e++) {
            float g0 = gelu_exact(acc[c8 * 8 + e].x);
            ushort u0 = f2bf(g0);
            h0[e] = (short)u0; l0[e] = (short)f2bf(g0 - bf2f(u0));
            float g1 = gelu_exact(acc[c8 * 8 + e].y);
            ushort u1 = f2bf(g1);
            h1[e] = (short)u1; l1[e] = (short)f2bf(g1 - bf2f(u1));
        }
        size_t b0 = (size_t)n * D + h * CPH + c8 * 8;
        *(short8*)&o96h[b0] = h0;     *(short8*)&o96l[b0] = l0;
        *(short8*)&o96h[b0 + D] = h1; *(short8*)&o96l[b0 + D] = l1;
    }
}

// ---------------- K6: proj 1x1 as bf16x3 MFMA + nearest 2x upsample ----------
// C[o, n] = sum_k wp[o,k] g[n,k];  A = wp rows (o), B = out96 rows (n)
// 128x128 tile, BK=32, same pipelined structure as k_qkv_mfma.
__global__ __launch_bounds__(256) void k_proj_mfma(
    const ushort* __restrict__ wph, const ushort* __restrict__ wpl,
    const ushort* __restrict__ o96h, const ushort* __restrict__ o96l,
    const float* __restrict__ bp, float* __restrict__ out) {
    __shared__ ushort lds[2][4][4096];
    const int tid = threadIdx.x;
    const int lane = tid & 63, wid = tid >> 6;
    const int wm = wid >> 1, wn = wid & 1;

    const int d   = blockIdx.x;        // 0..215
    const int xcd = d & 7;
    const int idx = d >> 3;            // 0..26
    const int nt  = xcd * 9 + idx / 3; // n-tile 0..71 (shares B panel per XCD)
    const int ot  = idx % 3;           // o-tile 0..2
    const int o0 = ot * 128;
    const int n0 = nt * 128;

    const ushort* srcs[4];
    srcs[0] = wph + (size_t)o0 * D;
    srcs[1] = wpl + (size_t)o0 * D;
    srcs[2] = o96h + (size_t)n0 * D;
    srcs[3] = o96l + (size_t)n0 * D;

    f32x4 acc[4][4];
#pragma unroll
    for (int i = 0; i < 4; i++)
#pragma unroll
        for (int j = 0; j < 4; j++) acc[i][j] = (f32x4){0.f, 0.f, 0.f, 0.f};

    int a_off[4], b_off[4];
#pragma unroll
    for (int f = 0; f < 4; f++) {
        int ra = wm * 64 + f * 16 + (lane & 15);
        a_off[f] = ra * 64 + ((((lane >> 4) ^ ((ra >> 1) & 3)) & 3) << 4);
        int rb = wn * 64 + f * 16 + (lane & 15);
        b_off[f] = rb * 64 + ((((lane >> 4) ^ ((rb >> 1) & 3)) & 3) << 4);
    }

    auto STAGE = [&](int buf, int kk) {
#pragma unroll
        for (int i = 0; i < 8; i++) {
            const int mat = i >> 1;
            const int cm  = ((i & 1) << 2) | wid;
            const int row = cm * 16 + (lane >> 2);
            const int scol = (((lane & 3) ^ ((row >> 1) & 3)) & 3) << 4;
            const ushort* src = srcs[mat] + (size_t)row * D + kk + (scol >> 1);
            __builtin_amdgcn_global_load_lds(
                (const __attribute__((address_space(1))) void*)src,
                (__attribute__((address_space(3))) void*)&lds[buf][mat][cm * 512],
                16, 0, 0);
        }
    };

    STAGE(0, 0);
    for (int t = 0; t < 12; ++t) {
        const int cur = t & 1;
        if (t < 11) {
            STAGE(cur ^ 1, (t + 1) * 32);
            asm volatile("s_waitcnt vmcnt(8)" ::: "memory");
        } else {
            asm volatile("s_waitcnt vmcnt(0)" ::: "memory");
        }
        __builtin_amdgcn_s_barrier();

        const char* bA0 = (const char*)&lds[cur][0][0];
        const char* bA1 = (const char*)&lds[cur][1][0];
        const char* bB0 = (const char*)&lds[cur][2][0];
        const char* bB1 = (const char*)&lds[cur][3][0];
        short8 A[2][4], B[2][4];
#pragma unroll
        for (int f = 0; f < 4; f++) {
            A[0][f] = *(const short8*)(bA0 + a_off[f]);
            A[1][f] = *(const short8*)(bA1 + a_off[f]);
            B[0][f] = *(const short8*)(bB0 + b_off[f]);
            B[1][f] = *(const short8*)(bB1 + b_off[f]);
        }
        __builtin_amdgcn_s_setprio(1);
#pragma unroll
        for (int fm = 0; fm < 4; fm++)
#pragma unroll
            for (int fn = 0; fn < 4; fn++) {
                acc[fm][fn] = __builtin_amdgcn_mfma_f32_16x16x32_bf16(A[0][fm], B[0][fn], acc[fm][fn], 0, 0, 0);
                acc[fm][fn] = __builtin_amdgcn_mfma_f32_16x16x32_bf16(A[0][fm], B[1][fn], acc[fm][fn], 0, 0, 0);
                acc[fm][fn] = __builtin_amdgcn_mfma_f32_16x16x32_bf16(A[1][fm], B[0][fn], acc[fm][fn], 0, 0, 0);
            }
        __builtin_amdgcn_s_setprio(0);
        asm volatile("s_waitcnt lgkmcnt(0)" ::: "memory");
        __builtin_amdgcn_s_barrier();
    }

    // epilogue: row = o (A-row), col = n (B-row); upsample 2x2 nearest
#pragma unroll
    for (int fn = 0; fn < 4; fn++) {
        const int n = n0 + wn * 64 + fn * 16 + (lane & 15);
        const int y = n / WP, xcol = n - y * WP;
        const size_t pbase = (size_t)(2 * y) * WFULL + 2 * xcol;
#pragma unroll
        for (int fm = 0; fm < 4; fm++) {
            f32x4 v = acc[fm][fn];
#pragma unroll
            for (int j = 0; j < 4; j++) {
                const int o = o0 + wm * 64 + fm * 16 + (lane >> 4) * 4 + j;
                const float val = v[j] + bp[o];
                float2 vv = make_float2(val, val);
                size_t base = (size_t)o * NF + pbase;
                *(float2*)&out[base] = vv;
                *(float2*)&out[base + WFULL] = vv;
            }
        }
    }
}

extern "C" void kernel_launch(void* const* d_in, const int* in_sizes, int n_in,
                              void* d_out, int out_size, void* d_ws, size_t ws_size,
                              hipStream_t stream) {
    (void)in_sizes; (void)n_in; (void)out_size; (void)ws_size;
    const float* x    = (const float*)d_in[0];
    const float* wq   = (const float*)d_in[1];
    const float* bq   = (const float*)d_in[2];
    const float* wd   = (const float*)d_in[3];
    const float* bd   = (const float*)d_in[4];
    const float* wp   = (const float*)d_in[5];
    const float* bp   = (const float*)d_in[6];
    const float* temp = (const float*)d_in[7];
    const float* a1   = (const float*)d_in[8];
    const float* a2   = (const float*)d_in[9];
    const float* a3   = (const float*)d_in[10];
    const float* a4   = (const float*)d_in[11];
    float* out = (float*)d_out;
    float* ws  = (float*)d_ws;

    // --- persistent region (beyond pooled), same 44.4 MB high-water as R3-R5:
    float* pooled = ws;                       // 10,616,832 floats (42.5 MB)
    float* S      = ws + 10616832;            // 18,432
    float* qn     = S + 18432;                // 384
    float* kn     = qn + 384;                 // 384
    float* Wc     = kn + 384;                 // 18,432
    ushort* wh    = (ushort*)(Wc + 18432);    // 442,368 bf16
    ushort* wl    = wh + 442368;              // 442,368 bf16

    // --- carved out of the pooled region once pooled is dead (after dwconv):
    ushort* o96h   = (ushort*)ws;                              // 3,538,944 bf16
    ushort* o96l   = o96h + 3538944;                           // 3,538,944 bf16
    float*  Spart  = (float*)((char*)ws + 14155776);           // 884,736 f32
    float*  qnpart = Spart + 884736;                           // 18,432 f32
    float*  knpart = qnpart + 18432;                           // 18,432 f32
    ushort* wph    = (ushort*)(knpart + 18432);                // 147,456 bf16
    ushort* wpl    = wph + 147456;                             // 147,456 bf16

    float* qkvdw = out;                       // q,k,v after dw conv staged in d_out
    // x split staged in d_out; dead before dwconv overwrites it
    ushort* xh = (ushort*)d_out;              // 14,155,776 bf16
    ushort* xl = xh + 14155776;               // 14,155,776 bf16

    hipLaunchKernelGGL(k_prep_w,    dim3(1728),    dim3(256), 0, stream, wq, wh, wl, QC * D);
    hipLaunchKernelGGL(k_prep_x,    dim3(288, 6),  dim3(256), 0, stream, x, xh, xl);
    hipLaunchKernelGGL(k_qkv_mfma,  dim3(2592),    dim3(256), 0, stream, xh, xl, wh, wl, bq, pooled);
    hipLaunchKernelGGL(k_dwconv,    dim3(41472),   dim3(256), 0, stream, pooled, wd, bd, qkvdw);
    hipLaunchKernelGGL(k_prep_w,    dim3(576),     dim3(256), 0, stream, wp, wph, wpl, D * D);
    hipLaunchKernelGGL(k_attn_part, dim3(48, 8),   dim3(256), 0, stream, qkvdw, Spart, qnpart, knpart);
    hipLaunchKernelGGL(k_red,       dim3(75),      dim3(256), 0, stream, Spart, qnpart, knpart, S, qn, kn);
    hipLaunchKernelGGL(k_softmax,   dim3(96),      dim3(256), 0, stream, S, qn, kn, temp, a1, a2, a3, a4, Wc);
    hipLaunchKernelGGL(k_av_gelu,   dim3(18, 8),   dim3(256), 0, stream, qkvdw, Wc, o96h, o96l);
    hipLaunchKernelGGL(k_proj_mfma, dim3(216),     dim3(256), 0, stream, wph, wpl, o96h, o96l, bp, out);
}

// Round 7
// 240.751 us; speedup vs baseline: 1.5470x; 1.1539x over previous
//
#include <hip/hip_runtime.h>
#include <hip/hip_bf16.h>
#include <math.h>

#define NH    8
#define CPH   48
#define D     384
#define QC    1152
#define HF    192
#define WFULL 192
#define HP    96
#define WP    96
#define NP    9216    // 96*96
#define NF    36864   // 192*192

typedef __attribute__((ext_vector_type(8))) short short8;
typedef __attribute__((ext_vector_type(4))) float f32x4;

__device__ __forceinline__ float gelu_exact(float v) {
    return 0.5f * v * (1.f + erff(v * 0.70710678118654752440f));
}
__device__ __forceinline__ ushort f2bf(float v) {
    __hip_bfloat16 h = __float2bfloat16(v);
    return *reinterpret_cast<ushort*>(&h);
}
__device__ __forceinline__ float bf2f(ushort u) {
    __hip_bfloat16 h = *reinterpret_cast<__hip_bfloat16*>(&u);
    return __bfloat162float(h);
}

// ---------------- P1: split fp32 -> bf16 hi/lo (standalone, used for wp) -----
__global__ __launch_bounds__(256) void k_prep_w(
    const float* __restrict__ w, ushort* __restrict__ wh, ushort* __restrict__ wl, int n) {
    int i = blockIdx.x * 256 + threadIdx.x;
    if (i < n) {
        float v = w[i];
        ushort h = f2bf(v);
        wh[i] = h;
        wl[i] = f2bf(v - bf2f(h));
    }
}

// ---------------- P2 (fused): wq split + x split/transpose -------------------
// blocks [0,1728): wq -> wh/wl.  blocks [1728, 3456): x -> xh/xl in
// n' = (py*96+px)*4 + (y&1)*2 + (x&1) pool-quad-contiguous pixel order.
__global__ __launch_bounds__(256) void k_prep(
    const float* __restrict__ wq, ushort* __restrict__ wh, ushort* __restrict__ wl,
    const float* __restrict__ x, ushort* __restrict__ xh, ushort* __restrict__ xl) {
    __shared__ float xf[64][128];   // 32 KB (unused by w-branch)
    const int tid = threadIdx.x;
    if (blockIdx.x < 1728) {
        int i = blockIdx.x * 256 + tid;          // n = 442368 = 1728*256 exact
        float v = wq[i];
        ushort h = f2bf(v);
        wh[i] = h;
        wl[i] = f2bf(v - bf2f(h));
        return;
    }
    const int e  = blockIdx.x - 1728;
    const int xt = e % 288, kt = e / 288;
    const int kk = kt * 64;
    const int q0 = xt * 32;                  // 32 pool quads (one pool row chunk)
    const int py = q0 / 96, px0 = q0 - py * 96;
    const int y0 = 2 * py, xcol0 = 2 * px0;
    const float* xb = x + (size_t)kk * NF + (size_t)y0 * WFULL + xcol0;
#pragma unroll
    for (int it = 0; it < 8; it++) {
        int li = tid + 256 * it;
        int ch = li >> 5, r = (li >> 4) & 1, c4 = (li & 15) * 4;
        float4 v = *(const float4*)&xb[(size_t)ch * NF + r * WFULL + c4];
        *(float4*)&xf[ch][r * 64 + c4] = v;
    }
    __syncthreads();
    const int row = tid >> 1, half = tid & 1;
    const int r = (row >> 1) & 1;
    const int col = (row >> 2) * 2 + (row & 1);
    const int src = r * 64 + col;
    const size_t np = (size_t)xt * 128 + row;
    ushort hbuf[32], lbuf[32];
#pragma unroll
    for (int j = 0; j < 32; j++) {
        float v = xf[half * 32 + j][src];
        ushort h = f2bf(v);
        hbuf[j] = h;
        lbuf[j] = f2bf(v - bf2f(h));
    }
    ushort* dh = xh + np * D + kk + half * 32;
    ushort* dl = xl + np * D + kk + half * 32;
#pragma unroll
    for (int j = 0; j < 4; j++) {
        *(short8*)&dh[j * 8] = *(const short8*)&hbuf[j * 8];
        *(short8*)&dl[j * 8] = *(const short8*)&lbuf[j * 8];
    }
}

// ---------------- K1: qkv 1x1 conv as bf16x3 MFMA GEMM + fused 2x2 maxpool ---
// Split into two half-M launches (mbase = 0 / 144) for per-kernel visibility.
__global__ __launch_bounds__(256) void k_qkv_mfma(
    const ushort* __restrict__ xh, const ushort* __restrict__ xl,
    const ushort* __restrict__ wh, const ushort* __restrict__ wl,
    const float* __restrict__ bq, float* __restrict__ pooled, int mbase) {
    __shared__ ushort lds[2][4][4096];  // [buf][Ah,Al,Bh,Bl][128 rows x 32 bf16]
    const int tid = threadIdx.x;
    const int lane = tid & 63, wid = tid >> 6;
    const int wm = wid >> 1, wn = wid & 1;

    const int d   = blockIdx.x;        // 0..1295, HW XCD = d % 8
    const int xcd = d & 7;
    const int idx = d >> 3;            // 0..161
    const int by  = mbase + xcd * 18 + idx / 9;
    const int bx  = idx % 9;
    const int n0 = bx * 128;
    const int m0 = by * 128;

    const ushort* srcs[4];
    srcs[0] = xh + (size_t)m0 * D;
    srcs[1] = xl + (size_t)m0 * D;
    srcs[2] = wh + (size_t)n0 * D;
    srcs[3] = wl + (size_t)n0 * D;

    f32x4 acc[4][4];
#pragma unroll
    for (int i = 0; i < 4; i++)
#pragma unroll
        for (int j = 0; j < 4; j++) acc[i][j] = (f32x4){0.f, 0.f, 0.f, 0.f};

    int a_off[4], b_off[4];
#pragma unroll
    for (int f = 0; f < 4; f++) {
        int ra = wm * 64 + f * 16 + (lane & 15);
        a_off[f] = ra * 64 + ((((lane >> 4) ^ ((ra >> 1) & 3)) & 3) << 4);
        int rb = wn * 64 + f * 16 + (lane & 15);
        b_off[f] = rb * 64 + ((((lane >> 4) ^ ((rb >> 1) & 3)) & 3) << 4);
    }

    auto STAGE = [&](int buf, int kk) {
#pragma unroll
        for (int i = 0; i < 8; i++) {
            const int mat = i >> 1;
            const int cm  = ((i & 1) << 2) | wid;
            const int row = cm * 16 + (lane >> 2);
            const int scol = (((lane & 3) ^ ((row >> 1) & 3)) & 3) << 4;
            const ushort* src = srcs[mat] + (size_t)row * D + kk + (scol >> 1);
            __builtin_amdgcn_global_load_lds(
                (const __attribute__((address_space(1))) void*)src,
                (__attribute__((address_space(3))) void*)&lds[buf][mat][cm * 512],
                16, 0, 0);
        }
    };

    STAGE(0, 0);
    for (int t = 0; t < 12; ++t) {
        const int cur = t & 1;
        if (t < 11) {
            STAGE(cur ^ 1, (t + 1) * 32);
            asm volatile("s_waitcnt vmcnt(8)" ::: "memory");
        } else {
            asm volatile("s_waitcnt vmcnt(0)" ::: "memory");
        }
        __builtin_amdgcn_s_barrier();

        const char* bA0 = (const char*)&lds[cur][0][0];
        const char* bA1 = (const char*)&lds[cur][1][0];
        const char* bB0 = (const char*)&lds[cur][2][0];
        const char* bB1 = (const char*)&lds[cur][3][0];
        short8 A[2][4], B[2][4];
#pragma unroll
        for (int f = 0; f < 4; f++) {
            A[0][f] = *(const short8*)(bA0 + a_off[f]);
            A[1][f] = *(const short8*)(bA1 + a_off[f]);
            B[0][f] = *(const short8*)(bB0 + b_off[f]);
            B[1][f] = *(const short8*)(bB1 + b_off[f]);
        }
        __builtin_amdgcn_s_setprio(1);
#pragma unroll
        for (int fm = 0; fm < 4; fm++)
#pragma unroll
            for (int fn = 0; fn < 4; fn++) {
                acc[fm][fn] = __builtin_amdgcn_mfma_f32_16x16x32_bf16(A[0][fm], B[0][fn], acc[fm][fn], 0, 0, 0);
                acc[fm][fn] = __builtin_amdgcn_mfma_f32_16x16x32_bf16(A[0][fm], B[1][fn], acc[fm][fn], 0, 0, 0);
                acc[fm][fn] = __builtin_amdgcn_mfma_f32_16x16x32_bf16(A[1][fm], B[0][fn], acc[fm][fn], 0, 0, 0);
            }
        __builtin_amdgcn_s_setprio(0);
        asm volatile("s_waitcnt lgkmcnt(0)" ::: "memory");
        __builtin_amdgcn_s_barrier();
    }

    const int p_base = by * 32 + wm * 16 + (lane >> 4);
#pragma unroll
    for (int fn = 0; fn < 4; fn++) {
        const int o = n0 + wn * 64 + fn * 16 + (lane & 15);
        const float b = bq[o];
#pragma unroll
        for (int fm = 0; fm < 4; fm++) {
            f32x4 v = acc[fm][fn];
            float mx = fmaxf(fmaxf(v.x, v.y), fmaxf(v.z, v.w)) + b;
            pooled[(size_t)o * NP + p_base + fm * 4] = mx;
        }
    }
}

// ---------------- K2: depthwise 3x3 conv, vectorized 4 outputs/thread --------
__global__ __launch_bounds__(256) void k_dwconv(
    const float* __restrict__ pooled, const float* __restrict__ wd,
    const float* __restrict__ bd, float* __restrict__ out) {
    int gid = blockIdx.x * 256 + threadIdx.x;   // 0 .. 2,654,207
    int xq = gid % 24, t = gid / 24;
    int y = t % 96, ch = t / 96;                // ch uniform per block (2304/ch)
    const float* src = pooled + (size_t)ch * NP;
    const float* w = wd + ch * 9;
    const int x0 = xq * 4;
    float b = bd[ch];
    float o0 = b, o1 = b, o2 = b, o3 = b;
#pragma unroll
    for (int dy = 0; dy < 3; dy++) {
        int yy = y + dy - 1;
        if (yy < 0 || yy >= HP) continue;
        const float* r = src + yy * WP;
        float4 c = *(const float4*)&r[x0];
        float lm = (x0 > 0) ? r[x0 - 1] : 0.f;
        float rm = (x0 < 92) ? r[x0 + 4] : 0.f;
        float w0 = w[dy * 3], w1 = w[dy * 3 + 1], w2 = w[dy * 3 + 2];
        o0 += w0 * lm  + w1 * c.x + w2 * c.y;
        o1 += w0 * c.x + w1 * c.y + w2 * c.z;
        o2 += w0 * c.y + w1 * c.z + w2 * c.w;
        o3 += w0 * c.z + w1 * c.w + w2 * rm;
    }
    *(float4*)&out[(size_t)ch * NP + y * WP + x0] = make_float4(o0, o1, o2, o3);
}

// ---------------- K3a: attn partials, no atomics -----------------------------
__global__ __launch_bounds__(256) void k_attn_part(
    const float* __restrict__ qkv, float* __restrict__ Spart,
    float* __restrict__ qnpart, float* __restrict__ knpart) {
    __shared__ float qs[48][196], ks[48][196];
    const int tid = threadIdx.x;
    const int p = blockIdx.x, h = blockIdx.y;
    const int n0 = p * 192;
    const float* qb = qkv + (size_t)(h * CPH) * NP + n0;
    const float* kb = qkv + (size_t)(D + h * CPH) * NP + n0;
#pragma unroll
    for (int it = 0; it < 9; it++) {
        int li = tid + 256 * it;             // 0..2303 float4s
        int row = li / 48, c4 = (li - row * 48) * 4;
        *(float4*)&qs[row][c4] = *(const float4*)&qb[(size_t)row * NP + c4];
        *(float4*)&ks[row][c4] = *(const float4*)&kb[(size_t)row * NP + c4];
    }
    __syncthreads();
    const int tr = (tid >> 4) * 3, tc = (tid & 15) * 3;
    float acc[3][3] = {};
    for (int n = 0; n < 192; n++) {
        float qv[3], kv[3];
#pragma unroll
        for (int i = 0; i < 3; i++) qv[i] = qs[tr + i][n];
#pragma unroll
        for (int j = 0; j < 3; j++) kv[j] = ks[tc + j][n];
#pragma unroll
        for (int i = 0; i < 3; i++)
#pragma unroll
            for (int j = 0; j < 3; j++) acc[i][j] += qv[i] * kv[j];
    }
    float* Sp = Spart + (size_t)(p * NH + h) * 2304;
#pragma unroll
    for (int i = 0; i < 3; i++)
#pragma unroll
        for (int j = 0; j < 3; j++)
            Sp[(tr + i) * CPH + tc + j] = acc[i][j];
    if (tid < 48) {
        float s = 0.f;
        for (int n = 0; n < 192; n++) s += qs[tid][n] * qs[tid][n];
        qnpart[(p * NH + h) * CPH + tid] = s;
    } else if (tid >= 64 && tid < 112) {
        int t2 = tid - 64;
        float s = 0.f;
        for (int n = 0; n < 192; n++) s += ks[t2][n] * ks[t2][n];
        knpart[(p * NH + h) * CPH + t2] = s;
    }
}

// ---------------- K4 (fused red+softmax): partials -> Wc ---------------------
__global__ __launch_bounds__(256) void k_softmax(
    const float* __restrict__ Spart, const float* __restrict__ qnpart,
    const float* __restrict__ knpart, const float* __restrict__ temp,
    const float* __restrict__ a1, const float* __restrict__ a2,
    const float* __restrict__ a3, const float* __restrict__ a4,
    float* __restrict__ Wc) {
    __shared__ float rowbuf[4][64];
    int lane = threadIdx.x & 63;
    int w = threadIdx.x >> 6;
    int row = blockIdx.x * 4 + w;
    int h = row / CPH, c = row % CPH;
    float a = -INFINITY;
    if (lane < CPH) {
        float s = 0.f, q2 = 0.f, k2 = 0.f;
        for (int p = 0; p < 48; p++) {
            int base = (p * NH + h);
            s  += Spart[(size_t)base * 2304 + c * CPH + lane];
            q2 += qnpart[base * CPH + c];
            k2 += knpart[base * CPH + lane];
        }
        float nq = fmaxf(sqrtf(fmaxf(q2, 0.f)), 1e-12f);
        float nk = fmaxf(sqrtf(fmaxf(k2, 0.f)), 1e-12f);
        a = s / (nq * nk) * temp[h];
    }
    rowbuf[w][lane] = a;
    __syncthreads();
    int rank = 0;
    float m = -INFINITY;
    for (int j = 0; j < CPH; j++) {
        float vj = rowbuf[w][j];
        m = fmaxf(m, vj);
        rank += (vj > a || (vj == a && j < lane)) ? 1 : 0;
    }
    float e = (lane < CPH) ? expf(a - m) : 0.f;
    float4 p;
    p.x = (rank < 24) ? e : 0.f;
    p.y = (rank < 32) ? e : 0.f;
    p.z = (rank < 36) ? e : 0.f;
    p.w = (rank < 38) ? e : 0.f;
#pragma unroll
    for (int off = 32; off > 0; off >>= 1) {
        p.x += __shfl_xor(p.x, off);
        p.y += __shfl_xor(p.y, off);
        p.z += __shfl_xor(p.z, off);
        p.w += __shfl_xor(p.w, off);
    }
    if (lane < CPH) {
        float wv = 0.f;
        if (rank < 24) wv += a1[0] / p.x;
        if (rank < 32) wv += a2[0] / p.y;
        if (rank < 36) wv += a3[0] / p.z;
        if (rank < 38) wv += a4[0] / p.w;
        Wc[(h * CPH + c) * CPH + lane] = e * wv;
    }
}

// ---------------- K5: gelu(Wc @ v) -> bf16 hi/lo rows [n][384] ---------------
__global__ __launch_bounds__(256) void k_av_gelu(
    const float* __restrict__ qkv, const float* __restrict__ Wc,
    ushort* __restrict__ o96h, ushort* __restrict__ o96l) {
    __shared__ float Wt[48][48];
    int tid = threadIdx.x;
    int h = blockIdx.y;
    int n = blockIdx.x * 512 + tid * 2;
#pragma unroll
    for (int it = 0; it < 9; it++) {
        int li = tid + 256 * it;
        if (li < 2304) {
            int dd = li / 48, cc = li - dd * 48;
            Wt[dd][cc] = Wc[(h * CPH + cc) * CPH + dd];
        }
    }
    __syncthreads();
    float2 acc[48];
#pragma unroll
    for (int c = 0; c < 48; c++) acc[c] = make_float2(0.f, 0.f);
    const float* vb = qkv + (size_t)(2 * D + h * CPH) * NP + n;
    for (int d = 0; d < 48; d++) {
        float2 vv = *(const float2*)&vb[(size_t)d * NP];
#pragma unroll
        for (int c4 = 0; c4 < 12; c4++) {
            float4 wv = *(const float4*)&Wt[d][c4 * 4];
            acc[c4 * 4 + 0].x += wv.x * vv.x; acc[c4 * 4 + 0].y += wv.x * vv.y;
            acc[c4 * 4 + 1].x += wv.y * vv.x; acc[c4 * 4 + 1].y += wv.y * vv.y;
            acc[c4 * 4 + 2].x += wv.z * vv.x; acc[c4 * 4 + 2].y += wv.z * vv.y;
            acc[c4 * 4 + 3].x += wv.w * vv.x; acc[c4 * 4 + 3].y += wv.w * vv.y;
        }
    }
#pragma unroll
    for (int c8 = 0; c8 < 6; c8++) {
        short8 h0, l0, h1, l1;
#pragma unroll
        for (int e = 0; e < 8; e++) {
            float g0 = gelu_exact(acc[c8 * 8 + e].x);
            ushort u0 = f2bf(g0);
            h0[e] = (short)u0; l0[e] = (short)f2bf(g0 - bf2f(u0));
            float g1 = gelu_exact(acc[c8 * 8 + e].y);
            ushort u1 = f2bf(g1);
            h1[e] = (short)u1; l1[e] = (short)f2bf(g1 - bf2f(u1));
        }
        size_t b0 = (size_t)n * D + h * CPH + c8 * 8;
        *(short8*)&o96h[b0] = h0;     *(short8*)&o96l[b0] = l0;
        *(short8*)&o96h[b0 + D] = h1; *(short8*)&o96l[b0 + D] = l1;
    }
}

// ---------------- K6: proj 1x1 as bf16x3 MFMA + nearest 2x upsample ----------
__global__ __launch_bounds__(256) void k_proj_mfma(
    const ushort* __restrict__ wph, const ushort* __restrict__ wpl,
    const ushort* __restrict__ o96h, const ushort* __restrict__ o96l,
    const float* __restrict__ bp, float* __restrict__ out) {
    __shared__ ushort lds[2][4][4096];
    const int tid = threadIdx.x;
    const int lane = tid & 63, wid = tid >> 6;
    const int wm = wid >> 1, wn = wid & 1;

    const int d   = blockIdx.x;        // 0..215
    const int xcd = d & 7;
    const int idx = d >> 3;            // 0..26
    const int nt  = xcd * 9 + idx / 3; // n-tile 0..71
    const int ot  = idx % 3;           // o-tile 0..2
    const int o0 = ot * 128;
    const int n0 = nt * 128;

    const ushort* srcs[4];
    srcs[0] = wph + (size_t)o0 * D;
    srcs[1] = wpl + (size_t)o0 * D;
    srcs[2] = o96h + (size_t)n0 * D;
    srcs[3] = o96l + (size_t)n0 * D;

    f32x4 acc[4][4];
#pragma unroll
    for (int i = 0; i < 4; i++)
#pragma unroll
        for (int j = 0; j < 4; j++) acc[i][j] = (f32x4){0.f, 0.f, 0.f, 0.f};

    int a_off[4], b_off[4];
#pragma unroll
    for (int f = 0; f < 4; f++) {
        int ra = wm * 64 + f * 16 + (lane & 15);
        a_off[f] = ra * 64 + ((((lane >> 4) ^ ((ra >> 1) & 3)) & 3) << 4);
        int rb = wn * 64 + f * 16 + (lane & 15);
        b_off[f] = rb * 64 + ((((lane >> 4) ^ ((rb >> 1) & 3)) & 3) << 4);
    }

    auto STAGE = [&](int buf, int kk) {
#pragma unroll
        for (int i = 0; i < 8; i++) {
            const int mat = i >> 1;
            const int cm  = ((i & 1) << 2) | wid;
            const int row = cm * 16 + (lane >> 2);
            const int scol = (((lane & 3) ^ ((row >> 1) & 3)) & 3) << 4;
            const ushort* src = srcs[mat] + (size_t)row * D + kk + (scol >> 1);
            __builtin_amdgcn_global_load_lds(
                (const __attribute__((address_space(1))) void*)src,
                (__attribute__((address_space(3))) void*)&lds[buf][mat][cm * 512],
                16, 0, 0);
        }
    };

    STAGE(0, 0);
    for (int t = 0; t < 12; ++t) {
        const int cur = t & 1;
        if (t < 11) {
            STAGE(cur ^ 1, (t + 1) * 32);
            asm volatile("s_waitcnt vmcnt(8)" ::: "memory");
        } else {
            asm volatile("s_waitcnt vmcnt(0)" ::: "memory");
        }
        __builtin_amdgcn_s_barrier();

        const char* bA0 = (const char*)&lds[cur][0][0];
        const char* bA1 = (const char*)&lds[cur][1][0];
        const char* bB0 = (const char*)&lds[cur][2][0];
        const char* bB1 = (const char*)&lds[cur][3][0];
        short8 A[2][4], B[2][4];
#pragma unroll
        for (int f = 0; f < 4; f++) {
            A[0][f] = *(const short8*)(bA0 + a_off[f]);
            A[1][f] = *(const short8*)(bA1 + a_off[f]);
            B[0][f] = *(const short8*)(bB0 + b_off[f]);
            B[1][f] = *(const short8*)(bB1 + b_off[f]);
        }
        __builtin_amdgcn_s_setprio(1);
#pragma unroll
        for (int fm = 0; fm < 4; fm++)
#pragma unroll
            for (int fn = 0; fn < 4; fn++) {
                acc[fm][fn] = __builtin_amdgcn_mfma_f32_16x16x32_bf16(A[0][fm], B[0][fn], acc[fm][fn], 0, 0, 0);
                acc[fm][fn] = __builtin_amdgcn_mfma_f32_16x16x32_bf16(A[0][fm], B[1][fn], acc[fm][fn], 0, 0, 0);
                acc[fm][fn] = __builtin_amdgcn_mfma_f32_16x16x32_bf16(A[1][fm], B[0][fn], acc[fm][fn], 0, 0, 0);
            }
        __builtin_amdgcn_s_setprio(0);
        asm volatile("s_waitcnt lgkmcnt(0)" ::: "memory");
        __builtin_amdgcn_s_barrier();
    }

#pragma unroll
    for (int fn = 0; fn < 4; fn++) {
        const int n = n0 + wn * 64 + fn * 16 + (lane & 15);
        const int y = n / WP, xcol = n - y * WP;
        const size_t pbase = (size_t)(2 * y) * WFULL + 2 * xcol;
#pragma unroll
        for (int fm = 0; fm < 4; fm++) {
            f32x4 v = acc[fm][fn];
#pragma unroll
            for (int j = 0; j < 4; j++) {
                const int o = o0 + wm * 64 + fm * 16 + (lane >> 4) * 4 + j;
                const float val = v[j] + bp[o];
                float2 vv = make_float2(val, val);
                size_t base = (size_t)o * NF + pbase;
                *(float2*)&out[base] = vv;
                *(float2*)&out[base + WFULL] = vv;
            }
        }
    }
}

extern "C" void kernel_launch(void* const* d_in, const int* in_sizes, int n_in,
                              void* d_out, int out_size, void* d_ws, size_t ws_size,
                              hipStream_t stream) {
    (void)in_sizes; (void)n_in; (void)out_size; (void)ws_size;
    const float* x    = (const float*)d_in[0];
    const float* wq   = (const float*)d_in[1];
    const float* bq   = (const float*)d_in[2];
    const float* wd   = (const float*)d_in[3];
    const float* bd   = (const float*)d_in[4];
    const float* wp   = (const float*)d_in[5];
    const float* bp   = (const float*)d_in[6];
    const float* temp = (const float*)d_in[7];
    const float* a1   = (const float*)d_in[8];
    const float* a2   = (const float*)d_in[9];
    const float* a3   = (const float*)d_in[10];
    const float* a4   = (const float*)d_in[11];
    float* out = (float*)d_out;
    float* ws  = (float*)d_ws;

    // persistent region (44.4 MB high-water, proven R3-R6):
    float* pooled = ws;                       // 10,616,832 floats (42.5 MB)
    float* Wc     = ws + 10616832;            // 18,432
    ushort* wh    = (ushort*)(Wc + 18432 + 19200);  // keep legacy offset, 884,736 bf16
    ushort* wl    = wh + 442368;

    // carved out of pooled once pooled is dead (after dwconv):
    ushort* o96h   = (ushort*)ws;                              // 3,538,944 bf16
    ushort* o96l   = o96h + 3538944;                           // 3,538,944 bf16
    float*  Spart  = (float*)((char*)ws + 14155776);           // 884,736 f32
    float*  qnpart = Spart + 884736;                           // 18,432 f32
    float*  knpart = qnpart + 18432;                           // 18,432 f32
    ushort* wph    = (ushort*)(knpart + 18432);                // 147,456 bf16
    ushort* wpl    = wph + 147456;                             // 147,456 bf16

    float* qkvdw = out;                       // q,k,v after dw conv staged in d_out
    ushort* xh = (ushort*)d_out;              // x hi staged in d_out (dead pre-dwconv)
    ushort* xl = xh + 14155776;

    hipLaunchKernelGGL(k_prep,      dim3(3456),    dim3(256), 0, stream, wq, wh, wl, x, xh, xl);
    hipLaunchKernelGGL(k_qkv_mfma,  dim3(1296),    dim3(256), 0, stream, xh, xl, wh, wl, bq, pooled, 0);
    hipLaunchKernelGGL(k_qkv_mfma,  dim3(1296),    dim3(256), 0, stream, xh, xl, wh, wl, bq, pooled, 144);
    hipLaunchKernelGGL(k_dwconv,    dim3(10368),   dim3(256), 0, stream, pooled, wd, bd, qkvdw);
    hipLaunchKernelGGL(k_prep_w,    dim3(576),     dim3(256), 0, stream, wp, wph, wpl, D * D);
    hipLaunchKernelGGL(k_attn_part, dim3(48, 8),   dim3(256), 0, stream, qkvdw, Spart, qnpart, knpart);
    hipLaunchKernelGGL(k_softmax,   dim3(96),      dim3(256), 0, stream, Spart, qnpart, knpart, temp, a1, a2, a3, a4, Wc);
    hipLaunchKernelGGL(k_av_gelu,   dim3(18, 8),   dim3(256), 0, stream, qkvdw, Wc, o96h, o96l);
    hipLaunchKernelGGL(k_proj_mfma, dim3(216),     dim3(256), 0, stream, wph, wpl, o96h, o96l, bp, out);
}